// Round 4
// baseline (542.724 us; speedup 1.0000x reference)
//
#include <hip/hip_runtime.h>
#include <stdint.h>

// ---- problem dims (fixed) ----
// B=4, T=S=2048, C=1024, H=16, D=64
#define NB 4
#define NT 2048
#define NC 1024
#define NH 16
#define ND 64
#define ACT_ELEMS (8388608ull)   /* B*T*C = 8M */
#define W_ELEMS   (1048576ull)   /* C*C = 1M  */

typedef __attribute__((ext_vector_type(8))) short short8;
typedef __attribute__((ext_vector_type(4))) float f32x4;
typedef __attribute__((ext_vector_type(2))) unsigned int u32x2;

__device__ __forceinline__ unsigned short f2bf(float x) {
    unsigned int u = __float_as_uint(x);
    u += 0x7fffu + ((u >> 16) & 1u);   // RNE
    return (unsigned short)(u >> 16);
}
__device__ __forceinline__ unsigned int f2bf2(float a, float b) {
    return (unsigned int)f2bf(a) | ((unsigned int)f2bf(b) << 16);
}
// cheap bf16x2 pack: round-half-up + byte-perm (3 VALU ops).
// valid for non-negative finite floats (exp() outputs); ties differ from RNE only.
__device__ __forceinline__ unsigned int bfpack(float a, float b) {
    unsigned int ua = __float_as_uint(a) + 0x8000u;
    unsigned int ub = __float_as_uint(b) + 0x8000u;
    return __builtin_amdgcn_perm(ub, ua, 0x07060302u);
}

#if defined(__has_builtin)
#if __has_builtin(__builtin_amdgcn_global_load_lds)
#define HAS_GLDS 1
#endif
#endif

// async global->LDS, 16B per lane. LDS dest = wave-uniform base + lane*16.
__device__ __forceinline__ void gl_lds16(const unsigned short* g, unsigned short* lds_wave_base) {
#ifdef HAS_GLDS
    __builtin_amdgcn_global_load_lds(
        (const __attribute__((address_space(1))) void*)g,
        (__attribute__((address_space(3))) void*)lds_wave_base, 16, 0, 0);
#else
    int lane = threadIdx.x & 63;
    *(short8*)(lds_wave_base + lane * 8) = *(const short8*)g;
#endif
}

// ---------------- convert all f32 inputs to bf16 once ----------------
__global__ __launch_bounds__(256) void cvt_all(const float* __restrict__ q,
                                               const float* __restrict__ k,
                                               const float* __restrict__ v,
                                               const float* __restrict__ wq,
                                               const float* __restrict__ wk,
                                               const float* __restrict__ wv,
                                               const float* __restrict__ wo,
                                               unsigned short* __restrict__ xb,
                                               unsigned short* __restrict__ wb) {
    int bid = blockIdx.x;
    const float* src;
    unsigned short* dst;
    int chunk;
    if (bid < 12288) {
        int z = bid >> 12; chunk = bid & 4095;
        src = (z == 0) ? q : (z == 1) ? k : v;
        dst = xb + (size_t)z * ACT_ELEMS;
    } else {
        int z = (bid - 12288) >> 9; chunk = (bid - 12288) & 511;
        src = (z == 0) ? wq : (z == 1) ? wk : (z == 2) ? wv : wo;
        dst = wb + (size_t)z * W_ELEMS;
    }
    size_t i = (size_t)chunk * 2048 + (size_t)threadIdx.x * 8;
    f32x4 f0 = *(const f32x4*)(src + i);
    f32x4 f1 = *(const f32x4*)(src + i + 4);
    u32x2 p0 = {f2bf2(f0[0], f0[1]), f2bf2(f0[2], f0[3])};
    u32x2 p1 = {f2bf2(f1[0], f1[1]), f2bf2(f1[2], f1[3])};
    *(u32x2*)(dst + i) = p0;
    *(u32x2*)(dst + i + 4) = p1;
}

// ---------------- NT GEMM: C[m,n] = sum_k A[m,k]*W[n,k] + bias[n] ----------------
template <int STORE>
__device__ __forceinline__ void gemm_body(const unsigned short* __restrict__ A,
                                          const unsigned short* __restrict__ W,
                                          const float* __restrict__ bias,
                                          unsigned short* __restrict__ dstb,
                                          float* __restrict__ dstf) {
    __shared__ unsigned short As[128 * 32];
    __shared__ unsigned short Bs[128 * 32];

    const int tid  = threadIdx.x;
    const int m0   = blockIdx.x * 128;
    const int n0   = blockIdx.y * 128;
    const int lane = tid & 63;
    const int wave = tid >> 6;
    const int col  = lane & 15;
    const int quad = lane >> 4;
    const int wr   = wave >> 1;
    const int wc   = wave & 1;

    f32x4 acc[4][4];
    const f32x4 fzero = {0.f, 0.f, 0.f, 0.f};
#pragma unroll
    for (int i = 0; i < 4; ++i)
#pragma unroll
        for (int j = 0; j < 4; ++j) acc[i][j] = fzero;

    for (int k0 = 0; k0 < NC; k0 += 32) {
#pragma unroll
        for (int r = 0; r < 2; ++r) {
            int g   = r * 256 + tid;
            int row = g >> 2;
            int cc  = (g & 3) * 8;
            unsigned short* abase = As + (size_t)(r * 2048 + wave * 512);
            unsigned short* bbase = Bs + (size_t)(r * 2048 + wave * 512);
            gl_lds16(A + (size_t)(m0 + row) * NC + k0 + cc, abase);
            gl_lds16(W + (size_t)(n0 + row) * NC + k0 + cc, bbase);
        }
        __syncthreads();

        short8 af[4], bf[4];
#pragma unroll
        for (int i = 0; i < 4; ++i)
            af[i] = *(const short8*)&As[(wr * 64 + i * 16 + col) * 32 + quad * 8];
#pragma unroll
        for (int j = 0; j < 4; ++j)
            bf[j] = *(const short8*)&Bs[(wc * 64 + j * 16 + col) * 32 + quad * 8];
#pragma unroll
        for (int i = 0; i < 4; ++i)
#pragma unroll
            for (int j = 0; j < 4; ++j)
                acc[i][j] = __builtin_amdgcn_mfma_f32_16x16x32_bf16(af[i], bf[j], acc[i][j], 0, 0, 0);
        __syncthreads();
    }

#pragma unroll
    for (int j = 0; j < 4; ++j) {
        int n = n0 + wc * 64 + j * 16 + col;
        float bv = bias[n];
#pragma unroll
        for (int i = 0; i < 4; ++i) {
#pragma unroll
            for (int r = 0; r < 4; ++r) {
                int m = m0 + wr * 64 + i * 16 + quad * 4 + r;
                float val = acc[i][j][r] + bv;
                if (STORE == 0) {
                    size_t idx = ((size_t)((m >> 11) * NH + (n >> 6)) * NT + (m & 2047)) * ND + (n & 63);
                    dstb[idx] = f2bf(val);
                } else {
                    dstf[(size_t)m * NC + n] = val;
                }
            }
        }
    }
}

__global__ __launch_bounds__(256) void proj_kernel(const unsigned short* __restrict__ xb,
                                                   const unsigned short* __restrict__ wb,
                                                   const float* __restrict__ b0,
                                                   const float* __restrict__ b1,
                                                   const float* __restrict__ b2,
                                                   unsigned short* __restrict__ qkv) {
    int z = blockIdx.z;
    const float* bias = (z == 0) ? b0 : (z == 1) ? b1 : b2;
    gemm_body<0>(xb + (size_t)z * ACT_ELEMS, wb + (size_t)z * W_ELEMS, bias,
                 qkv + (size_t)z * ACT_ELEMS, nullptr);
}

__global__ __launch_bounds__(256) void outproj_kernel(const unsigned short* __restrict__ ao,
                                                      const unsigned short* __restrict__ w,
                                                      const float* __restrict__ bias,
                                                      float* __restrict__ out) {
    gemm_body<1>(ao, w, bias, nullptr, out);
}

// ---------------- flash attention v4 ----------------
// grid (T/128, H, B), 256 threads, t=32/wave. No K LDS (direct global A-frags,
// L2-resident); no P LDS round-trip (S^T C-layout == PV B-operand k-mapping with
// k-slots j<4 -> sg_even, j>=4 -> sg_odd); V^T double-buffered in LDS with
// register prefetch; one barrier per s-tile; fixed-max softmax, deferred l.
__global__ __launch_bounds__(256, 3) void attn_kernel(const unsigned short* __restrict__ q,
                                                      const unsigned short* __restrict__ k,
                                                      const unsigned short* __restrict__ v,
                                                      const float* __restrict__ amask,
                                                      const unsigned char* __restrict__ kpm,
                                                      unsigned short* __restrict__ ao) {
    __shared__ unsigned short Vt[2][64 * 72];   // V^T [d][s], padded stride 72
    __shared__ float kpmF[NT];                  // key-padding bias (0 / -inf)

    const int tid  = threadIdx.x;
    const int lane = tid & 63;
    const int wave = tid >> 6;
    const int col  = lane & 15;
    const int quad = lane >> 4;

    const int b  = blockIdx.z;
    const int h  = blockIdx.y;
    const int t0 = blockIdx.x * 128;

    const size_t headbase = (size_t)(b * NH + h) * NT * ND;

    // ---- stage key-padding bias once ----
    {
        const unsigned char* kp8 = kpm + b * NT + tid * 8;
        f32x4 r0, r1;
#pragma unroll
        for (int j = 0; j < 4; ++j) r0[j] = kp8[j] ? -INFINITY : 0.0f;
#pragma unroll
        for (int j = 0; j < 4; ++j) r1[j] = kp8[4 + j] ? -INFINITY : 0.0f;
        *(f32x4*)&kpmF[tid * 8]     = r0;
        *(f32x4*)&kpmF[tid * 8 + 4] = r1;
    }

    // ---- Q B-operand frags (t = col), loaded once ----
    short8 qf[2][2];
#pragma unroll
    for (int tg = 0; tg < 2; ++tg) {
        const unsigned short* qr =
            q + headbase + (size_t)(t0 + wave * 32 + tg * 16 + col) * ND + quad * 8;
        qf[tg][0] = *(const short8*)qr;
        qf[tg][1] = *(const short8*)(qr + 32);
    }

    const f32x4 fzero = {0.f, 0.f, 0.f, 0.f};
    f32x4 O[2][4];   // O^T acc: [tg][dg], lane holds d = dg*16+quad*4+r, t = col
#pragma unroll
    for (int tg = 0; tg < 2; ++tg)
#pragma unroll
        for (int dg = 0; dg < 4; ++dg) O[tg][dg] = fzero;
    float lsum[2] = {0.f, 0.f};

    // V staging mapping: 256 threads cover 64s x 64d tile; s-pair + 8-d chunk.
    const int vsp = tid & 31;
    const int vd0 = (tid >> 5) * 8;

    // ---- prologue: stage V tile 0 ----
    {
        const unsigned short* vp = v + headbase + (size_t)(vsp * 2) * ND + vd0;
        short8 va = *(const short8*)vp;
        short8 vb2 = *(const short8*)(vp + ND);
        unsigned int* dst = (unsigned int*)Vt[0];
#pragma unroll
        for (int i = 0; i < 8; ++i)
            dst[(vd0 + i) * 36 + vsp] =
                (unsigned int)(unsigned short)va[i] | ((unsigned int)(unsigned short)vb2[i] << 16);
    }
    __syncthreads();

    int buf = 0;
    for (int s0 = 0; s0 < NT; s0 += 64) {
        // ---- prefetch next V tile into registers ----
        short8 vna, vnb;
        const bool last = (s0 + 64 >= NT);
        if (!last) {
            const unsigned short* vp = v + headbase + (size_t)(s0 + 64 + vsp * 2) * ND + vd0;
            vna = *(const short8*)vp;
            vnb = *(const short8*)(vp + ND);
        }

        const unsigned short* vbuf = Vt[buf];
#pragma unroll
        for (int sh = 0; sh < 2; ++sh) {   // two 32-s halves
            unsigned int pku[2][4];        // [tg][k-pair]: B-frag for PV
#pragma unroll
            for (int sp = 0; sp < 2; ++sp) {
                int sg = sh * 2 + sp;
                // K A-frag direct from global (L2-hit)
                const unsigned short* kr =
                    k + headbase + (size_t)(s0 + sg * 16 + col) * ND + quad * 8;
                short8 kf0 = *(const short8*)kr;
                short8 kf1 = *(const short8*)(kr + 32);
                f32x4 kb4 = *(const f32x4*)&kpmF[s0 + sg * 16 + quad * 4];
#pragma unroll
                for (int tg = 0; tg < 2; ++tg) {
                    f32x4 z = fzero;
                    z = __builtin_amdgcn_mfma_f32_16x16x32_bf16(kf0, qf[tg][0], z, 0, 0, 0);
                    z = __builtin_amdgcn_mfma_f32_16x16x32_bf16(kf1, qf[tg][1], z, 0, 0, 0);
                    int t = t0 + wave * 32 + tg * 16 + col;
                    f32x4 mv = *(const f32x4*)(amask + (size_t)t * NT + s0 + sg * 16 + quad * 4);
                    float p0 = __expf(z[0] * 0.125f + mv[0] + kb4[0]);
                    float p1 = __expf(z[1] * 0.125f + mv[1] + kb4[1]);
                    float p2 = __expf(z[2] * 0.125f + mv[2] + kb4[2]);
                    float p3 = __expf(z[3] * 0.125f + mv[3] + kb4[3]);
                    lsum[tg] += (p0 + p1) + (p2 + p3);
                    pku[tg][sp * 2]     = bfpack(p0, p1);
                    pku[tg][sp * 2 + 1] = bfpack(p2, p3);
                }
            }
            // ---- PV: O^T += V^T-frag (A) x P^T-frag (B), k-slots j<4 = sg even, j>=4 = sg odd ----
            union { unsigned int u[4]; short8 s8; } pb0, pb1;
#pragma unroll
            for (int i = 0; i < 4; ++i) { pb0.u[i] = pku[0][i]; pb1.u[i] = pku[1][i]; }
#pragma unroll
            for (int dg = 0; dg < 4; ++dg) {
                const unsigned short* vr = vbuf + (dg * 16 + col) * 72 + sh * 32 + quad * 4;
                union { uint64_t u[2]; short8 s8; } af;
                af.u[0] = *(const uint64_t*)vr;          // s = sh*32 + quad*4 + j
                af.u[1] = *(const uint64_t*)(vr + 16);   // s = sh*32 + 16 + quad*4 + j
                O[0][dg] = __builtin_amdgcn_mfma_f32_16x16x32_bf16(af.s8, pb0.s8, O[0][dg], 0, 0, 0);
                O[1][dg] = __builtin_amdgcn_mfma_f32_16x16x32_bf16(af.s8, pb1.s8, O[1][dg], 0, 0, 0);
            }
        }

        // ---- pack & write prefetched V to other buffer ----
        if (!last) {
            unsigned int* dst = (unsigned int*)Vt[buf ^ 1];
#pragma unroll
            for (int i = 0; i < 8; ++i)
                dst[(vd0 + i) * 36 + vsp] =
                    (unsigned int)(unsigned short)vna[i] | ((unsigned int)(unsigned short)vnb[i] << 16);
        }
        __syncthreads();
        buf ^= 1;
    }

    // ---- l reduction + epilogue (lane's t = col; d = dg*16+quad*4+r) ----
    float linv[2];
#pragma unroll
    for (int tg = 0; tg < 2; ++tg) {
        float s = lsum[tg];
        s += __shfl_xor(s, 16);
        s += __shfl_xor(s, 32);
        linv[tg] = 1.0f / s;
    }
#pragma unroll
    for (int tg = 0; tg < 2; ++tg) {
        int t = t0 + wave * 32 + tg * 16 + col;
#pragma unroll
        for (int dg = 0; dg < 4; ++dg) {
            u32x2 w;
            w[0] = bfpack(O[tg][dg][0] * linv[tg], O[tg][dg][1] * linv[tg]);
            w[1] = bfpack(O[tg][dg][2] * linv[tg], O[tg][dg][3] * linv[tg]);
            *(u32x2*)(ao + (size_t)(b * NT + t) * NC + h * ND + dg * 16 + quad * 4) = w;
        }
    }
}

// ---------------- launch ----------------
extern "C" void kernel_launch(void* const* d_in, const int* in_sizes, int n_in,
                              void* d_out, int out_size, void* d_ws, size_t ws_size,
                              hipStream_t stream) {
    const float* query = (const float*)d_in[0];
    const float* key_  = (const float*)d_in[1];
    const float* value = (const float*)d_in[2];
    const float* amask = (const float*)d_in[3];
    const unsigned char* kpm = (const unsigned char*)d_in[4];
    const float* Wq = (const float*)d_in[5];
    const float* bq = (const float*)d_in[6];
    const float* Wk = (const float*)d_in[7];
    const float* bk = (const float*)d_in[8];
    const float* Wv = (const float*)d_in[9];
    const float* bv = (const float*)d_in[10];
    const float* Wo = (const float*)d_in[11];
    const float* bo = (const float*)d_in[12];
    float* out = (float*)d_out;

    unsigned short* ws = (unsigned short*)d_ws;
    unsigned short* xb  = ws;                   // bf16 acts, 24M shorts
    unsigned short* qb  = ws + 3 * ACT_ELEMS;   // projected q,k,v (B,H,T,D)
    unsigned short* wb  = ws + 6 * ACT_ELEMS;   // 4 weights bf16
    unsigned short* aob = xb;                   // attn_out aliases dead xb

    cvt_all<<<14336, 256, 0, stream>>>(query, key_, value, Wq, Wk, Wv, Wo, xb, wb);

    dim3 pg(64, 8, 3);
    proj_kernel<<<pg, 256, 0, stream>>>(xb, wb, bq, bk, bv, qb);

    dim3 ag(NT / 128, NH, NB);
    attn_kernel<<<ag, 256, 0, stream>>>(qb, qb + ACT_ELEMS, qb + 2 * ACT_ELEMS,
                                        amask, kpm, aob);

    dim3 og(64, 8, 1);
    outproj_kernel<<<og, 256, 0, stream>>>(aob, wb + 3 * W_ELEMS, bo, out);
}